// Round 3
// baseline (324.600 us; speedup 1.0000x reference)
//
#include <hip/hip_runtime.h>
#include <hip/hip_bf16.h>

#define B_ROWS 8192
#define FEAT   1538

typedef float f32x4 __attribute__((ext_vector_type(4)));
typedef float f32x2 __attribute__((ext_vector_type(2)));
typedef short s16x8 __attribute__((ext_vector_type(8)));

#if __has_builtin(__builtin_amdgcn_exp2f)
#define EXP2(x) __builtin_amdgcn_exp2f(x)
#else
#define EXP2(x) exp2f(x)
#endif

__device__ __forceinline__ unsigned short f2bf(float x) {
    __hip_bfloat16 h = __float2bfloat16(x);
    return *reinterpret_cast<unsigned short*>(&h);
}

// ---------------------------------------------------------------------------
// Kernel 0: transpose+convert W_DA/W_DM (f32 [768][64]) -> bf16 WbT [2][64][768]
// so prep's MFMA B-fragments are single contiguous 16B loads. grid 128.
// ---------------------------------------------------------------------------
__global__ __launch_bounds__(256) void wconv_kernel(
    const float* __restrict__ W_DA, const float* __restrict__ W_DM,
    unsigned short* __restrict__ WbT)
{
    const int m   = blockIdx.x >> 6;     // 0 = DA, 1 = DM
    const int col = blockIdx.x & 63;
    const float* W = m ? W_DM : W_DA;
    unsigned short* dst = WbT + ((size_t)m * 64 + col) * 768;
#pragma unroll
    for (int i = 0; i < 3; ++i) {
        int k = i * 256 + threadIdx.x;
        dst[k] = f2bf(W[(size_t)k * 64 + col]);
    }
}

// ---------------------------------------------------------------------------
// Kernel A: per 16-row block -> fm, X, and bf16 Qp/Kp/VpT.
// Phase 1 (768x64 GEMMs x2) now via MFMA 16x16x32 bf16.
// block = 256 threads (4 waves). grid = 512.
// ---------------------------------------------------------------------------
__global__ __launch_bounds__(256) void prep_kernel(
    const float* __restrict__ bd, const float* __restrict__ fm_w, const float* __restrict__ fm_b,
    const float* __restrict__ b_DA, const float* __restrict__ b_DM,
    const unsigned short* __restrict__ WbT,
    const float* __restrict__ hDA, const float* __restrict__ hDM,
    const float* __restrict__ hCA, const float* __restrict__ hCM,
    const float* __restrict__ fvDA, const float* __restrict__ fvDM,
    const float* __restrict__ fvCA, const float* __restrict__ fvCM,
    const float* __restrict__ Qw, const float* __restrict__ Kw, const float* __restrict__ Vw,
    float* __restrict__ fm_out, unsigned short* __restrict__ Qp,
    unsigned short* __restrict__ Kp, unsigned short* __restrict__ VpT)
{
    __shared__ unsigned short s_bd16[16][1544];   // bf16 batch rows (pad for 16B stride)
    __shared__ float s_iDA [64][16];
    __shared__ float s_iDA2[64][16];
    __shared__ float s_iDM [64][16];
    __shared__ float s_iDM2[64][16];
    __shared__ float s_sc[16][4];                 // sB_DA, sB_DM, cA, cM per row
    __shared__ float s_fmrow[16];
    __shared__ float s_rsum[2][2][16];            // [mat][colhalf][row]
    __shared__ float s_X[64][16];
    __shared__ unsigned short s_vp[64][16];

    const int tid  = threadIdx.x;
    const int w    = tid >> 6;
    const int lane = tid & 63;
    const int l15  = lane & 15, lhi = lane >> 4;
    const int r0   = blockIdx.x * 16;

    // ---- Stage bd rows 0..1535 as bf16 into LDS; fm partial along the way.
    {
        const int srow = tid >> 4, scg = tid & 15;   // srow == w*4 + lhi
        const float* bdr = bd + (size_t)(r0 + srow) * FEAT;
        float fmp = 0.f;
#pragma unroll 4
        for (int s = 0; s < 24; ++s) {
            int c = (scg + s * 16) * 4;
            f32x2 v0 = *(const f32x2*)(bdr + c);
            f32x2 v1 = *(const f32x2*)(bdr + c + 2);
            f32x2 g0 = *(const f32x2*)(fm_w + c);
            f32x2 g1 = *(const f32x2*)(fm_w + c + 2);
            fmp += v0.x * g0.x + v0.y * g0.y + v1.x * g1.x + v1.y * g1.y;
            ushort4 p;
            p.x = f2bf(v0.x); p.y = f2bf(v0.y); p.z = f2bf(v1.x); p.w = f2bf(v1.y);
            *(ushort4*)&s_bd16[srow][c] = p;
        }
        fmp += __shfl_xor(fmp, 1, 64); fmp += __shfl_xor(fmp, 2, 64);
        fmp += __shfl_xor(fmp, 4, 64); fmp += __shfl_xor(fmp, 8, 64);
        if (l15 == 0) s_fmrow[srow] = fmp;
    }
    __syncthreads();

    // ---- Phase 1: inter = bd @ W (+bias) via MFMA.
    // wave: mat = w>>1 (DA/DM), ct2 = w&1 (cols 32*ct2..+31). 48 MFMA/wave.
    {
        const int mat = w >> 1;
        const int ct2 = w & 1;
        const unsigned short* WT = WbT + (size_t)mat * 64 * 768 + (size_t)(ct2 * 32) * 768;
        const int kb = mat * 768;
        f32x4 c0 = {0.f, 0.f, 0.f, 0.f}, c1 = {0.f, 0.f, 0.f, 0.f};
#pragma unroll 6
        for (int s = 0; s < 24; ++s) {
            s16x8 A  = *(const s16x8*)&s_bd16[l15][kb + s * 32 + lhi * 8];
            s16x8 B0 = *(const s16x8*)(WT + (size_t)l15 * 768 + s * 32 + lhi * 8);
            s16x8 B1 = *(const s16x8*)(WT + (size_t)(16 + l15) * 768 + s * 32 + lhi * 8);
            c0 = __builtin_amdgcn_mfma_f32_16x16x32_bf16(A, B0, c0, 0, 0, 0);
            c1 = __builtin_amdgcn_mfma_f32_16x16x32_bf16(A, B1, c1, 0, 0, 0);
        }
        const float* bb = mat ? b_DM : b_DA;
        const float bias0 = bb[ct2 * 32 + l15];
        const float bias1 = bb[ct2 * 32 + 16 + l15];
        float (*iA)[16]  = mat ? s_iDM  : s_iDA;
        float (*iA2)[16] = mat ? s_iDM2 : s_iDA2;
        float rsum[4];
#pragma unroll
        for (int reg = 0; reg < 4; ++reg) {
            const int row = lhi * 4 + reg;           // C-layout: col=l15, row=lhi*4+reg
            float v0 = c0[reg] + bias0;
            float v1 = c1[reg] + bias1;
            iA [ct2 * 32 + l15][row]      = v0;
            iA2[ct2 * 32 + l15][row]      = v0 * v0;
            iA [ct2 * 32 + 16 + l15][row] = v1;
            iA2[ct2 * 32 + 16 + l15][row] = v1 * v1;
            float rs = v0 + v1;                      // partial row-sum over this wave's 32 cols
            rs += __shfl_xor(rs, 1, 64); rs += __shfl_xor(rs, 2, 64);
            rs += __shfl_xor(rs, 4, 64); rs += __shfl_xor(rs, 8, 64);
            rsum[reg] = rs;
        }
        if (l15 == 0) {
#pragma unroll
            for (int reg = 0; reg < 4; ++reg)
                s_rsum[mat][ct2][lhi * 4 + reg] = rsum[reg];
        }
    }
    __syncthreads();

    if (tid < 16) {
        const int r = tid;
        float cA = bd[(size_t)(r0 + r) * FEAT + 1536];
        float cM = bd[(size_t)(r0 + r) * FEAT + 1537];
        s_sc[r][0] = s_rsum[0][0][r] + s_rsum[0][1][r];
        s_sc[r][1] = s_rsum[1][0][r] + s_rsum[1][1][r];
        s_sc[r][2] = cA; s_sc[r][3] = cM;
        fm_out[r0 + r] = s_fmrow[r] + cA * fm_w[1536] + cM * fm_w[1537] + fm_b[0];
    }
    __syncthreads();

    // ---- Phase 2: bi-pooling sums + X (wave w owns rows 4w..4w+3, lane = h)
    float sADA[4] = {0,0,0,0}, sqDA[4] = {0,0,0,0};
    float sADM[4] = {0,0,0,0}, sqDM[4] = {0,0,0,0};
    const int rbase = w * 4;
    for (int e2 = 0; e2 < 64; ++e2) {
        float ha = hDA[e2 * 64 + lane], hm = hDM[e2 * 64 + lane];
        float ha2 = ha * ha, hm2 = hm * hm;
        f32x4 ia  = *(const f32x4*)&s_iDA [e2][rbase];
        f32x4 ia2 = *(const f32x4*)&s_iDA2[e2][rbase];
        f32x4 im  = *(const f32x4*)&s_iDM [e2][rbase];
        f32x4 im2 = *(const f32x4*)&s_iDM2[e2][rbase];
#pragma unroll
        for (int rr = 0; rr < 4; ++rr) {
            sADA[rr] += ia[rr] * ha;  sqDA[rr] += ia2[rr] * ha2;
            sADM[rr] += im[rr] * hm;  sqDM[rr] += im2[rr] * hm2;
        }
    }
    {
        const float fva = fvDA[lane], fvm = fvDM[lane];
        const float fvca = fvCA[lane], fvcm = fvCM[lane];
        const float hca = hCA[lane],  hcm = hCM[lane];
#pragma unroll
        for (int rr = 0; rr < 4; ++rr) {
            int r = rbase + rr;
            float sBDA = s_sc[r][0], sBDM = s_sc[r][1];
            float cA = s_sc[r][2],   cM = s_sc[r][3];
            float biA = 0.5f * (sADA[rr] * sADA[rr] - sqDA[rr]);
            float biM = 0.5f * (sADM[rr] * sADM[rr] - sqDM[rr]);
            float X = biA + biM
                + sADA[rr] * (fvm * sBDM + fvca * cA + fvcm * cM)
                + sADM[rr] * (fva * sBDA + fvca * cA + fvcm * cM)
                + cA * hca * (fva * sBDA + fvm * sBDM + fvcm * cM)
                + cM * hcm * (fva * sBDA + fvm * sBDM + fvca * cA);
            s_X[lane][r] = X;
        }
    }
    __syncthreads();

    // ---- Phase 3: QKV projection (lane = output col j)
    float aQ[4] = {0,0,0,0}, aK[4] = {0,0,0,0}, aV[4] = {0,0,0,0};
    for (int h2 = 0; h2 < 64; ++h2) {
        float q = Qw[h2 * 64 + lane], k = Kw[h2 * 64 + lane], v = Vw[h2 * 64 + lane];
        f32x4 x = *(const f32x4*)&s_X[h2][rbase];
#pragma unroll
        for (int rr = 0; rr < 4; ++rr) {
            aQ[rr] += x[rr] * q; aK[rr] += x[rr] * k; aV[rr] += x[rr] * v;
        }
    }
    const float LOG2E = 1.4426950408889634f;
#pragma unroll
    for (int rr = 0; rr < 4; ++rr) {
        int r = rbase + rr;
        Qp[(size_t)(r0 + r) * 64 + lane] = f2bf(aQ[rr] * LOG2E);
        Kp[(size_t)(r0 + r) * 64 + lane] = f2bf(aK[rr]);
        s_vp[lane][r] = f2bf(aV[rr]);
    }
    __syncthreads();
    if (tid < 64) {
        const uint4* src = (const uint4*)&s_vp[tid][0];   // 16 bf16 = 32 B
        uint4* dst = (uint4*)(VpT + (size_t)tid * B_ROWS + r0);
        dst[0] = src[0]; dst[1] = src[1];
    }
}

// ---------------------------------------------------------------------------
// Kernel B: flash attention, split-K across blocks.
// grid = 512 qtiles x 4 key-splits = 2048 blocks; block = 4 waves.
// Each wave: 16 q-rows x 512 keys (8 iterations of 64). Partial (O,l) -> ws.
// ---------------------------------------------------------------------------
__global__ __launch_bounds__(256, 6) void attn_kernel(
    const unsigned short* __restrict__ Qp, const unsigned short* __restrict__ Kp,
    const unsigned short* __restrict__ VpT,
    float* __restrict__ Opart, float* __restrict__ lpart)
{
    __shared__ unsigned short s_P[4][16][72];   // per-wave P tile, padded rows
    __shared__ float s_O[4][16][64];
    __shared__ float s_l[4][16];

    const int tid = threadIdx.x;
    const int w = tid >> 6, lane = tid & 63;
    const int l15 = lane & 15, lhi = lane >> 4;
    const int qt = blockIdx.x >> 2, sp = blockIdx.x & 3;
    const int qr0 = qt * 16;

    s16x8 QA[2];
#pragma unroll
    for (int kk = 0; kk < 2; ++kk)
        QA[kk] = *(const s16x8*)(Qp + (size_t)(qr0 + l15) * 64 + kk * 32 + lhi * 8);

    f32x4 accO[4];
#pragma unroll
    for (int ht = 0; ht < 4; ++ht) accO[ht] = (f32x4){0.f, 0.f, 0.f, 0.f};
    float lp[4] = {0.f, 0.f, 0.f, 0.f};
    const f32x4 zero4 = (f32x4){0.f, 0.f, 0.f, 0.f};

    const int key0 = sp * 2048 + w * 512;
    for (int it = 0; it < 8; ++it) {
        const int kc0 = key0 + it * 64;
        s16x8 KB[4][2];
#pragma unroll
        for (int nt = 0; nt < 4; ++nt)
#pragma unroll
            for (int kk = 0; kk < 2; ++kk)
                KB[nt][kk] = *(const s16x8*)(Kp + (size_t)(kc0 + nt * 16 + l15) * 64 + kk * 32 + lhi * 8);

        f32x4 accS[4];
#pragma unroll
        for (int nt = 0; nt < 4; ++nt) {
            accS[nt] = __builtin_amdgcn_mfma_f32_16x16x32_bf16(QA[0], KB[nt][0], zero4, 0, 0, 0);
            accS[nt] = __builtin_amdgcn_mfma_f32_16x16x32_bf16(QA[1], KB[nt][1], accS[nt], 0, 0, 0);
        }
        // P = exp2(S); Qp carries log2(e). C-layout: row=(lane>>4)*4+reg, col=lane&15.
#pragma unroll
        for (int nt = 0; nt < 4; ++nt)
#pragma unroll
            for (int reg = 0; reg < 4; ++reg) {
                float p = EXP2(accS[nt][reg]);
                lp[reg] += p;
                s_P[w][lhi * 4 + reg][nt * 16 + l15] = f2bf(p);
            }
        s16x8 PA[2];
#pragma unroll
        for (int kk = 0; kk < 2; ++kk)
            PA[kk] = *(const s16x8*)&s_P[w][l15][kk * 32 + lhi * 8];
        s16x8 VB[4][2];
#pragma unroll
        for (int ht = 0; ht < 4; ++ht)
#pragma unroll
            for (int kk = 0; kk < 2; ++kk)
                VB[ht][kk] = *(const s16x8*)(VpT + (size_t)(ht * 16 + l15) * B_ROWS + kc0 + kk * 32 + lhi * 8);
#pragma unroll
        for (int ht = 0; ht < 4; ++ht) {
            accO[ht] = __builtin_amdgcn_mfma_f32_16x16x32_bf16(PA[0], VB[ht][0], accO[ht], 0, 0, 0);
            accO[ht] = __builtin_amdgcn_mfma_f32_16x16x32_bf16(PA[1], VB[ht][1], accO[ht], 0, 0, 0);
        }
    }

    // deferred row-sum reduce (rows live in 16-lane groups)
#pragma unroll
    for (int reg = 0; reg < 4; ++reg) {
        float v = lp[reg];
        v += __shfl_xor(v, 1, 64); v += __shfl_xor(v, 2, 64);
        v += __shfl_xor(v, 4, 64); v += __shfl_xor(v, 8, 64);
        lp[reg] = v;
    }
    if (l15 == 0) {
#pragma unroll
        for (int reg = 0; reg < 4; ++reg) s_l[w][lhi * 4 + reg] = lp[reg];
    }
#pragma unroll
    for (int ht = 0; ht < 4; ++ht)
#pragma unroll
        for (int reg = 0; reg < 4; ++reg)
            s_O[w][lhi * 4 + reg][ht * 16 + l15] = accO[ht][reg];
    __syncthreads();

    // block partial = sum of 4 waves -> workspace
    const int pb = (qt * 4 + sp) * 16;
#pragma unroll
    for (int i = 0; i < 4; ++i) {
        int idx = i * 256 + tid, r = idx >> 6, c = idx & 63;
        Opart[(size_t)(pb + r) * 64 + c] =
            s_O[0][r][c] + s_O[1][r][c] + s_O[2][r][c] + s_O[3][r][c];
    }
    if (tid < 16)
        lpart[pb + tid] = s_l[0][tid] + s_l[1][tid] + s_l[2][tid] + s_l[3][tid];
}

// ---------------------------------------------------------------------------
// Kernel C: merge 4 key-splits + epilogue relu((vw@W1)/sqrt(1+eps)), h@W2,
// sigmoid(fm + .). grid = 512, block = 256.
// ---------------------------------------------------------------------------
__global__ __launch_bounds__(256) void merge_kernel(
    const float* __restrict__ Opart, const float* __restrict__ lpart,
    const float* __restrict__ fm,
    const float* __restrict__ W1, const float* __restrict__ b1,
    const float* __restrict__ W2, const float* __restrict__ b2,
    float* __restrict__ out)
{
    __shared__ float s_Os[16][64];
    __shared__ float s_L[16];
    __shared__ float s_ep[16][17];

    const int tid = threadIdx.x;
    const int qt = blockIdx.x;
    const int pb = qt * 4 * 16;

#pragma unroll
    for (int i = 0; i < 4; ++i) {
        int idx = i * 256 + tid, r = idx >> 6, c = idx & 63;
        float o = 0.f;
#pragma unroll
        for (int sp2 = 0; sp2 < 4; ++sp2)
            o += Opart[(size_t)(pb + sp2 * 16 + r) * 64 + c];
        s_Os[r][c] = o;
    }
    if (tid < 16) {
        float L = 0.f;
#pragma unroll
        for (int sp2 = 0; sp2 < 4; ++sp2) L += lpart[pb + sp2 * 16 + tid];
        s_L[tid] = L;
    }
    __syncthreads();
    {
        const int r = tid & 15, jg = tid >> 4;
        const float invL = 1.0f / s_L[r];
        const float invs = 0.9999950000374997f;   // 1/sqrt(1+1e-5)
        float d[4] = {0.f, 0.f, 0.f, 0.f};
        for (int c = 0; c < 64; ++c) {
            float o = s_Os[r][c];
#pragma unroll
            for (int jj = 0; jj < 4; ++jj) d[jj] += o * W1[c * 64 + jg * 4 + jj];
        }
        float acc = 0.f;
#pragma unroll
        for (int jj = 0; jj < 4; ++jj) {
            int j = jg * 4 + jj;
            float hv = invs * (d[jj] * invL + b1[j]);
            hv = fmaxf(hv, 0.f);
            acc += hv * W2[j];
        }
        s_ep[r][jg] = acc;
    }
    __syncthreads();
    if (tid < 16) {
        int r = tid;
        float s = 0.f;
#pragma unroll
        for (int jg = 0; jg < 16; ++jg) s += s_ep[r][jg];
        float z = fm[qt * 16 + r] + s + b2[0];
        out[qt * 16 + r] = 1.0f / (1.0f + __expf(-z));
    }
}

extern "C" void kernel_launch(void* const* d_in, const int* in_sizes, int n_in,
                              void* d_out, int out_size, void* d_ws, size_t ws_size,
                              hipStream_t stream) {
    const float* bd   = (const float*)d_in[0];
    const float* fm_w = (const float*)d_in[1];
    const float* fm_b = (const float*)d_in[2];
    const float* W_DA = (const float*)d_in[3];
    const float* b_DA = (const float*)d_in[4];
    const float* W_DM = (const float*)d_in[5];
    const float* b_DM = (const float*)d_in[6];
    const float* hDA  = (const float*)d_in[7];
    const float* hDM  = (const float*)d_in[8];
    const float* hCA  = (const float*)d_in[9];
    const float* hCM  = (const float*)d_in[10];
    const float* fvDA = (const float*)d_in[11];
    const float* fvDM = (const float*)d_in[12];
    const float* fvCA = (const float*)d_in[13];
    const float* fvCM = (const float*)d_in[14];
    const float* Qw   = (const float*)d_in[15];
    const float* Kw   = (const float*)d_in[16];
    const float* Vw   = (const float*)d_in[17];
    const float* W1   = (const float*)d_in[18];
    const float* b1   = (const float*)d_in[19];
    const float* W2   = (const float*)d_in[20];
    const float* b2   = (const float*)d_in[21];

    char* ws = (char*)d_ws;
    float*          fmv   = (float*)ws;                                   // 32 KB
    unsigned short* Qp    = (unsigned short*)(ws + (32u<<10));            // 1 MB
    unsigned short* Kp    = (unsigned short*)(ws + (32u<<10) + (1u<<20)); // 1 MB
    unsigned short* VpT   = (unsigned short*)(ws + (32u<<10) + (2u<<20)); // 1 MB
    unsigned short* WbT   = (unsigned short*)(ws + (32u<<10) + (3u<<20)); // 192 KB (reserve 256 KB)
    float*          Opart = (float*)(ws + (32u<<10) + (3u<<20) + (256u<<10)); // 8 MB
    float*          lpart = (float*)(ws + (32u<<10) + (3u<<20) + (256u<<10) + (8u<<20)); // 128 KB

    hipLaunchKernelGGL(wconv_kernel, dim3(128), dim3(256), 0, stream,
        W_DA, W_DM, WbT);

    hipLaunchKernelGGL(prep_kernel, dim3(512), dim3(256), 0, stream,
        bd, fm_w, fm_b, b_DA, b_DM, WbT, hDA, hDM, hCA, hCM,
        fvDA, fvDM, fvCA, fvCM, Qw, Kw, Vw, fmv, Qp, Kp, VpT);

    hipLaunchKernelGGL(attn_kernel, dim3(2048), dim3(256), 0, stream,
        Qp, Kp, VpT, Opart, lpart);

    hipLaunchKernelGGL(merge_kernel, dim3(512), dim3(256), 0, stream,
        Opart, lpart, fmv, W1, b1, W2, b2, (float*)d_out);
}

// Round 5
// 186.989 us; speedup vs baseline: 1.7359x; 1.7359x over previous
//
#include <hip/hip_runtime.h>
#include <hip/hip_bf16.h>

#define B_ROWS 8192
#define FEAT   1538

typedef float f32x4 __attribute__((ext_vector_type(4)));
typedef float f32x2 __attribute__((ext_vector_type(2)));
typedef short s16x8 __attribute__((ext_vector_type(8)));

#if __has_builtin(__builtin_amdgcn_exp2f)
#define EXP2(x) __builtin_amdgcn_exp2f(x)
#else
#define EXP2(x) exp2f(x)
#endif

__device__ __forceinline__ unsigned short f2bf(float x) {
    __hip_bfloat16 h = __float2bfloat16(x);
    return *reinterpret_cast<unsigned short*>(&h);
}

// async global->LDS, 16B per lane. LDS dest must be wave-uniform base
// (HW writes base + lane*16); global src is per-lane.
__device__ __forceinline__ void gl_lds16(const void* g, void* l) {
    __builtin_amdgcn_global_load_lds(
        (const __attribute__((address_space(1))) unsigned int*)g,
        (__attribute__((address_space(3))) unsigned int*)l, 16, 0, 0);
}

// ---------------------------------------------------------------------------
// Kernel 0: transpose+convert W_DA/W_DM (f32 [768][64]) -> bf16 WbT [2][64][768]
// ---------------------------------------------------------------------------
__global__ __launch_bounds__(256) void wconv_kernel(
    const float* __restrict__ W_DA, const float* __restrict__ W_DM,
    unsigned short* __restrict__ WbT)
{
    const int m   = blockIdx.x >> 6;     // 0 = DA, 1 = DM
    const int col = blockIdx.x & 63;
    const float* W = m ? W_DM : W_DA;
    unsigned short* dst = WbT + ((size_t)m * 64 + col) * 768;
#pragma unroll
    for (int i = 0; i < 3; ++i) {
        int k = i * 256 + threadIdx.x;
        dst[k] = f2bf(W[(size_t)k * 64 + col]);
    }
}

// ---------------------------------------------------------------------------
// Kernel A: per 16-row block -> fm, X, and bf16 Qp/Kp/VpT.
// block = 256 threads (4 waves). grid = 512.
// ---------------------------------------------------------------------------
__global__ __launch_bounds__(256) void prep_kernel(
    const float* __restrict__ bd, const float* __restrict__ fm_w, const float* __restrict__ fm_b,
    const float* __restrict__ b_DA, const float* __restrict__ b_DM,
    const unsigned short* __restrict__ WbT,
    const float* __restrict__ hDA, const float* __restrict__ hDM,
    const float* __restrict__ hCA, const float* __restrict__ hCM,
    const float* __restrict__ fvDA, const float* __restrict__ fvDM,
    const float* __restrict__ fvCA, const float* __restrict__ fvCM,
    const float* __restrict__ Qw, const float* __restrict__ Kw, const float* __restrict__ Vw,
    float* __restrict__ fm_out, unsigned short* __restrict__ Qp,
    unsigned short* __restrict__ Kp, unsigned short* __restrict__ VpT)
{
    __shared__ unsigned short s_bd16[16][1544];   // bf16 batch rows (pad for 16B stride)
    __shared__ float s_iDA [64][16];
    __shared__ float s_iDA2[64][16];
    __shared__ float s_iDM [64][16];
    __shared__ float s_iDM2[64][16];
    __shared__ float s_sc[16][4];                 // sB_DA, sB_DM, cA, cM per row
    __shared__ float s_fmrow[16];
    __shared__ float s_rsum[2][2][16];            // [mat][colhalf][row]
    __shared__ float s_X[64][16];
    __shared__ unsigned short s_vp[64][16];

    const int tid  = threadIdx.x;
    const int w    = tid >> 6;
    const int lane = tid & 63;
    const int l15  = lane & 15, lhi = lane >> 4;
    const int r0   = blockIdx.x * 16;

    // ---- Stage bd rows 0..1535 as bf16 into LDS; fm partial along the way.
    {
        const int srow = tid >> 4, scg = tid & 15;   // srow == w*4 + lhi
        const float* bdr = bd + (size_t)(r0 + srow) * FEAT;
        float fmp = 0.f;
#pragma unroll 8
        for (int s = 0; s < 24; ++s) {
            int c = (scg + s * 16) * 4;
            f32x2 v0 = *(const f32x2*)(bdr + c);
            f32x2 v1 = *(const f32x2*)(bdr + c + 2);
            f32x2 g0 = *(const f32x2*)(fm_w + c);
            f32x2 g1 = *(const f32x2*)(fm_w + c + 2);
            fmp += v0.x * g0.x + v0.y * g0.y + v1.x * g1.x + v1.y * g1.y;
            ushort4 p;
            p.x = f2bf(v0.x); p.y = f2bf(v0.y); p.z = f2bf(v1.x); p.w = f2bf(v1.y);
            *(ushort4*)&s_bd16[srow][c] = p;
        }
        fmp += __shfl_xor(fmp, 1, 64); fmp += __shfl_xor(fmp, 2, 64);
        fmp += __shfl_xor(fmp, 4, 64); fmp += __shfl_xor(fmp, 8, 64);
        if (l15 == 0) s_fmrow[srow] = fmp;
    }
    __syncthreads();

    // ---- Phase 1: inter = bd @ W (+bias) via MFMA.
    {
        const int mat = w >> 1;
        const int ct2 = w & 1;
        const unsigned short* WT = WbT + (size_t)mat * 64 * 768 + (size_t)(ct2 * 32) * 768;
        const int kb = mat * 768;
        f32x4 c0 = {0.f, 0.f, 0.f, 0.f}, c1 = {0.f, 0.f, 0.f, 0.f};
#pragma unroll 6
        for (int s = 0; s < 24; ++s) {
            s16x8 A  = *(const s16x8*)&s_bd16[l15][kb + s * 32 + lhi * 8];
            s16x8 B0 = *(const s16x8*)(WT + (size_t)l15 * 768 + s * 32 + lhi * 8);
            s16x8 B1 = *(const s16x8*)(WT + (size_t)(16 + l15) * 768 + s * 32 + lhi * 8);
            c0 = __builtin_amdgcn_mfma_f32_16x16x32_bf16(A, B0, c0, 0, 0, 0);
            c1 = __builtin_amdgcn_mfma_f32_16x16x32_bf16(A, B1, c1, 0, 0, 0);
        }
        const float* bb = mat ? b_DM : b_DA;
        const float bias0 = bb[ct2 * 32 + l15];
        const float bias1 = bb[ct2 * 32 + 16 + l15];
        float (*iA)[16]  = mat ? s_iDM  : s_iDA;
        float (*iA2)[16] = mat ? s_iDM2 : s_iDA2;
        float rsum[4];
#pragma unroll
        for (int reg = 0; reg < 4; ++reg) {
            const int row = lhi * 4 + reg;           // C-layout: col=l15, row=lhi*4+reg
            float v0 = c0[reg] + bias0;
            float v1 = c1[reg] + bias1;
            iA [ct2 * 32 + l15][row]      = v0;
            iA2[ct2 * 32 + l15][row]      = v0 * v0;
            iA [ct2 * 32 + 16 + l15][row] = v1;
            iA2[ct2 * 32 + 16 + l15][row] = v1 * v1;
            float rs = v0 + v1;
            rs += __shfl_xor(rs, 1, 64); rs += __shfl_xor(rs, 2, 64);
            rs += __shfl_xor(rs, 4, 64); rs += __shfl_xor(rs, 8, 64);
            rsum[reg] = rs;
        }
        if (l15 == 0) {
#pragma unroll
            for (int reg = 0; reg < 4; ++reg)
                s_rsum[mat][ct2][lhi * 4 + reg] = rsum[reg];
        }
    }
    __syncthreads();

    if (tid < 16) {
        const int r = tid;
        float cA = bd[(size_t)(r0 + r) * FEAT + 1536];
        float cM = bd[(size_t)(r0 + r) * FEAT + 1537];
        s_sc[r][0] = s_rsum[0][0][r] + s_rsum[0][1][r];
        s_sc[r][1] = s_rsum[1][0][r] + s_rsum[1][1][r];
        s_sc[r][2] = cA; s_sc[r][3] = cM;
        fm_out[r0 + r] = s_fmrow[r] + cA * fm_w[1536] + cM * fm_w[1537] + fm_b[0];
    }
    __syncthreads();

    // ---- Phase 2: bi-pooling sums + X (wave w owns rows 4w..4w+3, lane = h)
    float sADA[4] = {0,0,0,0}, sqDA[4] = {0,0,0,0};
    float sADM[4] = {0,0,0,0}, sqDM[4] = {0,0,0,0};
    const int rbase = w * 4;
#pragma unroll 8
    for (int e2 = 0; e2 < 64; ++e2) {
        float ha = hDA[e2 * 64 + lane], hm = hDM[e2 * 64 + lane];
        float ha2 = ha * ha, hm2 = hm * hm;
        f32x4 ia  = *(const f32x4*)&s_iDA [e2][rbase];
        f32x4 ia2 = *(const f32x4*)&s_iDA2[e2][rbase];
        f32x4 im  = *(const f32x4*)&s_iDM [e2][rbase];
        f32x4 im2 = *(const f32x4*)&s_iDM2[e2][rbase];
#pragma unroll
        for (int rr = 0; rr < 4; ++rr) {
            sADA[rr] += ia[rr] * ha;  sqDA[rr] += ia2[rr] * ha2;
            sADM[rr] += im[rr] * hm;  sqDM[rr] += im2[rr] * hm2;
        }
    }
    {
        const float fva = fvDA[lane], fvm = fvDM[lane];
        const float fvca = fvCA[lane], fvcm = fvCM[lane];
        const float hca = hCA[lane],  hcm = hCM[lane];
#pragma unroll
        for (int rr = 0; rr < 4; ++rr) {
            int r = rbase + rr;
            float sBDA = s_sc[r][0], sBDM = s_sc[r][1];
            float cA = s_sc[r][2],   cM = s_sc[r][3];
            float biA = 0.5f * (sADA[rr] * sADA[rr] - sqDA[rr]);
            float biM = 0.5f * (sADM[rr] * sADM[rr] - sqDM[rr]);
            float X = biA + biM
                + sADA[rr] * (fvm * sBDM + fvca * cA + fvcm * cM)
                + sADM[rr] * (fva * sBDA + fvca * cA + fvcm * cM)
                + cA * hca * (fva * sBDA + fvm * sBDM + fvcm * cM)
                + cM * hcm * (fva * sBDA + fvm * sBDM + fvca * cA);
            s_X[lane][r] = X;
        }
    }
    __syncthreads();

    // ---- Phase 3: QKV projection (lane = output col j)
    float aQ[4] = {0,0,0,0}, aK[4] = {0,0,0,0}, aV[4] = {0,0,0,0};
#pragma unroll 8
    for (int h2 = 0; h2 < 64; ++h2) {
        float q = Qw[h2 * 64 + lane], k = Kw[h2 * 64 + lane], v = Vw[h2 * 64 + lane];
        f32x4 x = *(const f32x4*)&s_X[h2][rbase];
#pragma unroll
        for (int rr = 0; rr < 4; ++rr) {
            aQ[rr] += x[rr] * q; aK[rr] += x[rr] * k; aV[rr] += x[rr] * v;
        }
    }
    const float LOG2E = 1.4426950408889634f;
#pragma unroll
    for (int rr = 0; rr < 4; ++rr) {
        int r = rbase + rr;
        Qp[(size_t)(r0 + r) * 64 + lane] = f2bf(aQ[rr] * LOG2E);
        Kp[(size_t)(r0 + r) * 64 + lane] = f2bf(aK[rr]);
        s_vp[lane][r] = f2bf(aV[rr]);
    }
    __syncthreads();
    if (tid < 64) {
        const uint4* src = (const uint4*)&s_vp[tid][0];   // 16 bf16 = 32 B
        uint4* dst = (uint4*)(VpT + (size_t)tid * B_ROWS + r0);
        dst[0] = src[0]; dst[1] = src[1];
    }
}

// ---------------------------------------------------------------------------
// Kernel B: flash attention, block = 64 q-rows (4 waves x 16), 4-way key
// split. K/V staged block-wide in LDS via global_load_lds (2-phase dbuf,
// T2 swizzle = pre-swizzled global source + swizzled ds_read, linear dest).
// grid = 128 qblocks x 4 splits = 512. Partial (O,l) per wave -> ws.
// ---------------------------------------------------------------------------
__global__ __launch_bounds__(256, 2) void attn_kernel(
    const unsigned short* __restrict__ Qp, const unsigned short* __restrict__ Kp,
    const unsigned short* __restrict__ VpT,
    float* __restrict__ Opart, float* __restrict__ lpart)
{
    __shared__ unsigned short s_K[2][64][64];   // [buf][key][d]   (swizzled rows)
    __shared__ unsigned short s_V[2][64][64];   // [buf][d][key]   (swizzled rows)
    __shared__ unsigned short s_P[4][16][72];   // per-wave P tile, padded rows

    const int tid = threadIdx.x;
    const int w = tid >> 6, lane = tid & 63;
    const int l15 = lane & 15, lhi = lane >> 4;
    const int qb = blockIdx.x >> 2, sp = blockIdx.x & 3;
    const int qrow0 = qb * 64 + w * 16;          // this wave's 16 q-rows
    const int key0 = sp * 2048;

    // staging source pattern: lane -> (row8 = lane>>3, chunk c16 = lane&7),
    // global col byte pre-swizzled so linear LDS ends up XOR-swizzled.
    const int r8  = lane >> 3, c16 = lane & 7;
    const int swz_st = (c16 * 16) ^ (r8 << 4);   // within 128B row
    const int swz_rd = (l15 & 7) << 4;           // read-side XOR

    s16x8 QA[2];
#pragma unroll
    for (int kk = 0; kk < 2; ++kk)
        QA[kk] = *(const s16x8*)(Qp + (size_t)(qrow0 + l15) * 64 + kk * 32 + lhi * 8);

    f32x4 accO[4];
#pragma unroll
    for (int ht = 0; ht < 4; ++ht) accO[ht] = (f32x4){0.f, 0.f, 0.f, 0.f};
    float lp[4] = {0.f, 0.f, 0.f, 0.f};
    const f32x4 zero4 = (f32x4){0.f, 0.f, 0.f, 0.f};

    // stage one 64-key tile (K: 8KB, V^T: 8KB) -- 4 gload16 per wave
    auto STAGE = [&](int buf, int t) {
        const int kc0 = key0 + t * 64;
#pragma unroll
        for (int j = 0; j < 2; ++j) {
            const int row = w * 16 + j * 8 + r8;                 // 0..63
            const char* gk = (const char*)Kp + (size_t)(kc0 + row) * 128 + swz_st;
            gl_lds16(gk, &s_K[buf][w * 16 + j * 8][0]);
            const char* gv = (const char*)VpT + (size_t)row * (B_ROWS * 2)
                             + (size_t)kc0 * 2 + swz_st;
            gl_lds16(gv, &s_V[buf][w * 16 + j * 8][0]);
        }
    };

    auto COMPUTE = [&](int buf) {
        const char* Kb = (const char*)&s_K[buf][0][0];
        const char* Vb = (const char*)&s_V[buf][0][0];
        f32x4 accS[4];
#pragma unroll
        for (int nt = 0; nt < 4; ++nt) {
            const int rb = (nt * 16 + l15) * 128;
            s16x8 k0 = *(const s16x8*)(Kb + rb + ((lhi * 16)      ^ swz_rd));
            s16x8 k1 = *(const s16x8*)(Kb + rb + ((64 + lhi * 16) ^ swz_rd));
            accS[nt] = __builtin_amdgcn_mfma_f32_16x16x32_bf16(QA[0], k0, zero4, 0, 0, 0);
            accS[nt] = __builtin_amdgcn_mfma_f32_16x16x32_bf16(QA[1], k1, accS[nt], 0, 0, 0);
        }
        // P = exp2(S); Qp carries log2(e). C-layout: row=lhi*4+reg, col=l15.
#pragma unroll
        for (int nt = 0; nt < 4; ++nt)
#pragma unroll
            for (int reg = 0; reg < 4; ++reg) {
                float p = EXP2(accS[nt][reg]);
                lp[reg] += p;
                s_P[w][lhi * 4 + reg][nt * 16 + l15] = f2bf(p);
            }
        s16x8 PA[2];
#pragma unroll
        for (int kk = 0; kk < 2; ++kk)
            PA[kk] = *(const s16x8*)&s_P[w][l15][kk * 32 + lhi * 8];
#pragma unroll
        for (int ht = 0; ht < 4; ++ht) {
            const int rb = (ht * 16 + l15) * 128;
            s16x8 v0 = *(const s16x8*)(Vb + rb + ((lhi * 16)      ^ swz_rd));
            s16x8 v1 = *(const s16x8*)(Vb + rb + ((64 + lhi * 16) ^ swz_rd));
            accO[ht] = __builtin_amdgcn_mfma_f32_16x16x32_bf16(PA[0], v0, accO[ht], 0, 0, 0);
            accO[ht] = __builtin_amdgcn_mfma_f32_16x16x32_bf16(PA[1], v1, accO[ht], 0, 0, 0);
        }
    };

    STAGE(0, 0);
    asm volatile("s_waitcnt vmcnt(0)" ::: "memory");
    __syncthreads();
    int cur = 0;
#pragma unroll 2
    for (int t = 0; t < 32; ++t) {
        if (t < 31) STAGE(cur ^ 1, t + 1);       // prefetch next tile (async)
        COMPUTE(cur);
        asm volatile("s_waitcnt vmcnt(0)" ::: "memory");
        __syncthreads();
        cur ^= 1;
    }

    // row-sum reduce over l15 groups; lanes l15==0 hold rows lhi*4+reg
#pragma unroll
    for (int reg = 0; reg < 4; ++reg) {
        float v = lp[reg];
        v += __shfl_xor(v, 1, 64); v += __shfl_xor(v, 2, 64);
        v += __shfl_xor(v, 4, 64); v += __shfl_xor(v, 8, 64);
        lp[reg] = v;
    }
    if (l15 == 0) {
#pragma unroll
        for (int reg = 0; reg < 4; ++reg)
            lpart[(size_t)sp * B_ROWS + qrow0 + lhi * 4 + reg] = lp[reg];
    }
#pragma unroll
    for (int ht = 0; ht < 4; ++ht)
#pragma unroll
        for (int reg = 0; reg < 4; ++reg)
            Opart[(size_t)sp * (B_ROWS * 64)
                  + (size_t)(qrow0 + lhi * 4 + reg) * 64 + ht * 16 + l15] = accO[ht][reg];
}

// ---------------------------------------------------------------------------
// Kernel C: merge 4 key-splits + epilogue relu((vw@W1)/sqrt(1+eps)), h@W2,
// sigmoid(fm + .). grid = 512 (16 rows each), block = 256.
// ---------------------------------------------------------------------------
__global__ __launch_bounds__(256) void merge_kernel(
    const float* __restrict__ Opart, const float* __restrict__ lpart,
    const float* __restrict__ fm,
    const float* __restrict__ W1, const float* __restrict__ b1,
    const float* __restrict__ W2, const float* __restrict__ b2,
    float* __restrict__ out)
{
    __shared__ float s_Os[16][64];
    __shared__ float s_L[16];
    __shared__ float s_ep[16][17];

    const int tid = threadIdx.x;
    const int qt = blockIdx.x;
    const int row0 = qt * 16;

#pragma unroll
    for (int i = 0; i < 4; ++i) {
        int idx = i * 256 + tid, r = idx >> 6, c = idx & 63;
        float o = 0.f;
#pragma unroll
        for (int sp2 = 0; sp2 < 4; ++sp2)
            o += Opart[(size_t)sp2 * (B_ROWS * 64) + (size_t)(row0 + r) * 64 + c];
        s_Os[r][c] = o;
    }
    if (tid < 16) {
        float L = 0.f;
#pragma unroll
        for (int sp2 = 0; sp2 < 4; ++sp2) L += lpart[(size_t)sp2 * B_ROWS + row0 + tid];
        s_L[tid] = L;
    }
    __syncthreads();
    {
        const int r = tid & 15, jg = tid >> 4;
        const float invL = 1.0f / s_L[r];
        const float invs = 0.9999950000374997f;   // 1/sqrt(1+1e-5)
        float d[4] = {0.f, 0.f, 0.f, 0.f};
#pragma unroll 8
        for (int c = 0; c < 64; ++c) {
            float o = s_Os[r][c];
#pragma unroll
            for (int jj = 0; jj < 4; ++jj) d[jj] += o * W1[c * 64 + jg * 4 + jj];
        }
        float acc = 0.f;
#pragma unroll
        for (int jj = 0; jj < 4; ++jj) {
            int j = jg * 4 + jj;
            float hv = invs * (d[jj] * invL + b1[j]);
            hv = fmaxf(hv, 0.f);
            acc += hv * W2[j];
        }
        s_ep[r][jg] = acc;
    }
    __syncthreads();
    if (tid < 16) {
        int r = tid;
        float s = 0.f;
#pragma unroll
        for (int jg = 0; jg < 16; ++jg) s += s_ep[r][jg];
        float z = fm[row0 + r] + s + b2[0];
        out[row0 + r] = 1.0f / (1.0f + __expf(-z));
    }
}

extern "C" void kernel_launch(void* const* d_in, const int* in_sizes, int n_in,
                              void* d_out, int out_size, void* d_ws, size_t ws_size,
                              hipStream_t stream) {
    const float* bd   = (const float*)d_in[0];
    const float* fm_w = (const float*)d_in[1];
    const float* fm_b = (const float*)d_in[2];
    const float* W_DA = (const float*)d_in[3];
    const float* b_DA = (const float*)d_in[4];
    const float* W_DM = (const float*)d_in[5];
    const float* b_DM = (const float*)d_in[6];
    const float* hDA  = (const float*)d_in[7];
    const float* hDM  = (const float*)d_in[8];
    const float* hCA  = (const float*)d_in[9];
    const float* hCM  = (const float*)d_in[10];
    const float* fvDA = (const float*)d_in[11];
    const float* fvDM = (const float*)d_in[12];
    const float* fvCA = (const float*)d_in[13];
    const float* fvCM = (const float*)d_in[14];
    const float* Qw   = (const float*)d_in[15];
    const float* Kw   = (const float*)d_in[16];
    const float* Vw   = (const float*)d_in[17];
    const float* W1   = (const float*)d_in[18];
    const float* b1   = (const float*)d_in[19];
    const float* W2   = (const float*)d_in[20];
    const float* b2   = (const float*)d_in[21];

    char* ws = (char*)d_ws;
    float*          fmv   = (float*)ws;                                   // 32 KB
    unsigned short* Qp    = (unsigned short*)(ws + (32u<<10));            // 1 MB
    unsigned short* Kp    = (unsigned short*)(ws + (32u<<10) + (1u<<20)); // 1 MB
    unsigned short* VpT   = (unsigned short*)(ws + (32u<<10) + (2u<<20)); // 1 MB
    unsigned short* WbT   = (unsigned short*)(ws + (32u<<10) + (3u<<20)); // 192 KB (reserve 256 KB)
    float*          Opart = (float*)(ws + (32u<<10) + (3u<<20) + (256u<<10)); // 8 MB
    float*          lpart = (float*)(ws + (32u<<10) + (3u<<20) + (256u<<10) + (8u<<20)); // 128 KB

    hipLaunchKernelGGL(wconv_kernel, dim3(128), dim3(256), 0, stream,
        W_DA, W_DM, WbT);

    hipLaunchKernelGGL(prep_kernel, dim3(512), dim3(256), 0, stream,
        bd, fm_w, fm_b, b_DA, b_DM, WbT, hDA, hDM, hCA, hCM,
        fvDA, fvDM, fvCA, fvCM, Qw, Kw, Vw, fmv, Qp, Kp, VpT);

    hipLaunchKernelGGL(attn_kernel, dim3(512), dim3(256), 0, stream,
        Qp, Kp, VpT, Opart, lpart);

    hipLaunchKernelGGL(merge_kernel, dim3(512), dim3(256), 0, stream,
        Opart, lpart, fmv, W1, b1, W2, b2, (float*)d_out);
}

// Round 6
// 185.732 us; speedup vs baseline: 1.7477x; 1.0068x over previous
//
#include <hip/hip_runtime.h>
#include <hip/hip_bf16.h>

#define B_ROWS 8192
#define FEAT   1538

typedef float f32x4 __attribute__((ext_vector_type(4)));
typedef float f32x2 __attribute__((ext_vector_type(2)));
typedef short s16x8 __attribute__((ext_vector_type(8)));

#if __has_builtin(__builtin_amdgcn_exp2f)
#define EXP2(x) __builtin_amdgcn_exp2f(x)
#else
#define EXP2(x) exp2f(x)
#endif

__device__ __forceinline__ unsigned short f2bf(float x) {
    __hip_bfloat16 h = __float2bfloat16(x);
    return *reinterpret_cast<unsigned short*>(&h);
}

// async global->LDS, 16B per lane. LDS dest must be wave-uniform base
// (HW writes base + lane*16); global src is per-lane.
__device__ __forceinline__ void gl_lds16(const void* g, void* l) {
    __builtin_amdgcn_global_load_lds(
        (const __attribute__((address_space(1))) unsigned int*)g,
        (__attribute__((address_space(3))) unsigned int*)l, 16, 0, 0);
}

// ---------------------------------------------------------------------------
// Kernel 0: transpose+convert W_DA/W_DM (f32 [768][64]) -> bf16 WbT [2][64][768]
// ---------------------------------------------------------------------------
__global__ __launch_bounds__(256) void wconv_kernel(
    const float* __restrict__ W_DA, const float* __restrict__ W_DM,
    unsigned short* __restrict__ WbT)
{
    const int m   = blockIdx.x >> 6;     // 0 = DA, 1 = DM
    const int col = blockIdx.x & 63;
    const float* W = m ? W_DM : W_DA;
    unsigned short* dst = WbT + ((size_t)m * 64 + col) * 768;
#pragma unroll
    for (int i = 0; i < 3; ++i) {
        int k = i * 256 + threadIdx.x;
        dst[k] = f2bf(W[(size_t)k * 64 + col]);
    }
}

// ---------------------------------------------------------------------------
// Kernel A: per 16-row block -> fm, X, and bf16 Qp/Kp/VpT.
// block = 256 threads (4 waves). grid = 512.   (unchanged from R5)
// ---------------------------------------------------------------------------
__global__ __launch_bounds__(256) void prep_kernel(
    const float* __restrict__ bd, const float* __restrict__ fm_w, const float* __restrict__ fm_b,
    const float* __restrict__ b_DA, const float* __restrict__ b_DM,
    const unsigned short* __restrict__ WbT,
    const float* __restrict__ hDA, const float* __restrict__ hDM,
    const float* __restrict__ hCA, const float* __restrict__ hCM,
    const float* __restrict__ fvDA, const float* __restrict__ fvDM,
    const float* __restrict__ fvCA, const float* __restrict__ fvCM,
    const float* __restrict__ Qw, const float* __restrict__ Kw, const float* __restrict__ Vw,
    float* __restrict__ fm_out, unsigned short* __restrict__ Qp,
    unsigned short* __restrict__ Kp, unsigned short* __restrict__ VpT)
{
    __shared__ unsigned short s_bd16[16][1544];   // bf16 batch rows (pad for 16B stride)
    __shared__ float s_iDA [64][16];
    __shared__ float s_iDA2[64][16];
    __shared__ float s_iDM [64][16];
    __shared__ float s_iDM2[64][16];
    __shared__ float s_sc[16][4];                 // sB_DA, sB_DM, cA, cM per row
    __shared__ float s_fmrow[16];
    __shared__ float s_rsum[2][2][16];            // [mat][colhalf][row]
    __shared__ float s_X[64][16];
    __shared__ unsigned short s_vp[64][16];

    const int tid  = threadIdx.x;
    const int w    = tid >> 6;
    const int lane = tid & 63;
    const int l15  = lane & 15, lhi = lane >> 4;
    const int r0   = blockIdx.x * 16;

    // ---- Stage bd rows 0..1535 as bf16 into LDS; fm partial along the way.
    {
        const int srow = tid >> 4, scg = tid & 15;   // srow == w*4 + lhi
        const float* bdr = bd + (size_t)(r0 + srow) * FEAT;
        float fmp = 0.f;
#pragma unroll 8
        for (int s = 0; s < 24; ++s) {
            int c = (scg + s * 16) * 4;
            f32x2 v0 = *(const f32x2*)(bdr + c);
            f32x2 v1 = *(const f32x2*)(bdr + c + 2);
            f32x2 g0 = *(const f32x2*)(fm_w + c);
            f32x2 g1 = *(const f32x2*)(fm_w + c + 2);
            fmp += v0.x * g0.x + v0.y * g0.y + v1.x * g1.x + v1.y * g1.y;
            ushort4 p;
            p.x = f2bf(v0.x); p.y = f2bf(v0.y); p.z = f2bf(v1.x); p.w = f2bf(v1.y);
            *(ushort4*)&s_bd16[srow][c] = p;
        }
        fmp += __shfl_xor(fmp, 1, 64); fmp += __shfl_xor(fmp, 2, 64);
        fmp += __shfl_xor(fmp, 4, 64); fmp += __shfl_xor(fmp, 8, 64);
        if (l15 == 0) s_fmrow[srow] = fmp;
    }
    __syncthreads();

    // ---- Phase 1: inter = bd @ W (+bias) via MFMA.
    {
        const int mat = w >> 1;
        const int ct2 = w & 1;
        const unsigned short* WT = WbT + (size_t)mat * 64 * 768 + (size_t)(ct2 * 32) * 768;
        const int kb = mat * 768;
        f32x4 c0 = {0.f, 0.f, 0.f, 0.f}, c1 = {0.f, 0.f, 0.f, 0.f};
#pragma unroll 6
        for (int s = 0; s < 24; ++s) {
            s16x8 A  = *(const s16x8*)&s_bd16[l15][kb + s * 32 + lhi * 8];
            s16x8 B0 = *(const s16x8*)(WT + (size_t)l15 * 768 + s * 32 + lhi * 8);
            s16x8 B1 = *(const s16x8*)(WT + (size_t)(16 + l15) * 768 + s * 32 + lhi * 8);
            c0 = __builtin_amdgcn_mfma_f32_16x16x32_bf16(A, B0, c0, 0, 0, 0);
            c1 = __builtin_amdgcn_mfma_f32_16x16x32_bf16(A, B1, c1, 0, 0, 0);
        }
        const float* bb = mat ? b_DM : b_DA;
        const float bias0 = bb[ct2 * 32 + l15];
        const float bias1 = bb[ct2 * 32 + 16 + l15];
        float (*iA)[16]  = mat ? s_iDM  : s_iDA;
        float (*iA2)[16] = mat ? s_iDM2 : s_iDA2;
        float rsum[4];
#pragma unroll
        for (int reg = 0; reg < 4; ++reg) {
            const int row = lhi * 4 + reg;           // C-layout: col=l15, row=lhi*4+reg
            float v0 = c0[reg] + bias0;
            float v1 = c1[reg] + bias1;
            iA [ct2 * 32 + l15][row]      = v0;
            iA2[ct2 * 32 + l15][row]      = v0 * v0;
            iA [ct2 * 32 + 16 + l15][row] = v1;
            iA2[ct2 * 32 + 16 + l15][row] = v1 * v1;
            float rs = v0 + v1;
            rs += __shfl_xor(rs, 1, 64); rs += __shfl_xor(rs, 2, 64);
            rs += __shfl_xor(rs, 4, 64); rs += __shfl_xor(rs, 8, 64);
            rsum[reg] = rs;
        }
        if (l15 == 0) {
#pragma unroll
            for (int reg = 0; reg < 4; ++reg)
                s_rsum[mat][ct2][lhi * 4 + reg] = rsum[reg];
        }
    }
    __syncthreads();

    if (tid < 16) {
        const int r = tid;
        float cA = bd[(size_t)(r0 + r) * FEAT + 1536];
        float cM = bd[(size_t)(r0 + r) * FEAT + 1537];
        s_sc[r][0] = s_rsum[0][0][r] + s_rsum[0][1][r];
        s_sc[r][1] = s_rsum[1][0][r] + s_rsum[1][1][r];
        s_sc[r][2] = cA; s_sc[r][3] = cM;
        fm_out[r0 + r] = s_fmrow[r] + cA * fm_w[1536] + cM * fm_w[1537] + fm_b[0];
    }
    __syncthreads();

    // ---- Phase 2: bi-pooling sums + X (wave w owns rows 4w..4w+3, lane = h)
    float sADA[4] = {0,0,0,0}, sqDA[4] = {0,0,0,0};
    float sADM[4] = {0,0,0,0}, sqDM[4] = {0,0,0,0};
    const int rbase = w * 4;
#pragma unroll 8
    for (int e2 = 0; e2 < 64; ++e2) {
        float ha = hDA[e2 * 64 + lane], hm = hDM[e2 * 64 + lane];
        float ha2 = ha * ha, hm2 = hm * hm;
        f32x4 ia  = *(const f32x4*)&s_iDA [e2][rbase];
        f32x4 ia2 = *(const f32x4*)&s_iDA2[e2][rbase];
        f32x4 im  = *(const f32x4*)&s_iDM [e2][rbase];
        f32x4 im2 = *(const f32x4*)&s_iDM2[e2][rbase];
#pragma unroll
        for (int rr = 0; rr < 4; ++rr) {
            sADA[rr] += ia[rr] * ha;  sqDA[rr] += ia2[rr] * ha2;
            sADM[rr] += im[rr] * hm;  sqDM[rr] += im2[rr] * hm2;
        }
    }
    {
        const float fva = fvDA[lane], fvm = fvDM[lane];
        const float fvca = fvCA[lane], fvcm = fvCM[lane];
        const float hca = hCA[lane],  hcm = hCM[lane];
#pragma unroll
        for (int rr = 0; rr < 4; ++rr) {
            int r = rbase + rr;
            float sBDA = s_sc[r][0], sBDM = s_sc[r][1];
            float cA = s_sc[r][2],   cM = s_sc[r][3];
            float biA = 0.5f * (sADA[rr] * sADA[rr] - sqDA[rr]);
            float biM = 0.5f * (sADM[rr] * sADM[rr] - sqDM[rr]);
            float X = biA + biM
                + sADA[rr] * (fvm * sBDM + fvca * cA + fvcm * cM)
                + sADM[rr] * (fva * sBDA + fvca * cA + fvcm * cM)
                + cA * hca * (fva * sBDA + fvm * sBDM + fvcm * cM)
                + cM * hcm * (fva * sBDA + fvm * sBDM + fvca * cA);
            s_X[lane][r] = X;
        }
    }
    __syncthreads();

    // ---- Phase 3: QKV projection (lane = output col j)
    float aQ[4] = {0,0,0,0}, aK[4] = {0,0,0,0}, aV[4] = {0,0,0,0};
#pragma unroll 8
    for (int h2 = 0; h2 < 64; ++h2) {
        float q = Qw[h2 * 64 + lane], k = Kw[h2 * 64 + lane], v = Vw[h2 * 64 + lane];
        f32x4 x = *(const f32x4*)&s_X[h2][rbase];
#pragma unroll
        for (int rr = 0; rr < 4; ++rr) {
            aQ[rr] += x[rr] * q; aK[rr] += x[rr] * k; aV[rr] += x[rr] * v;
        }
    }
    const float LOG2E = 1.4426950408889634f;
#pragma unroll
    for (int rr = 0; rr < 4; ++rr) {
        int r = rbase + rr;
        Qp[(size_t)(r0 + r) * 64 + lane] = f2bf(aQ[rr] * LOG2E);
        Kp[(size_t)(r0 + r) * 64 + lane] = f2bf(aK[rr]);
        s_vp[lane][r] = f2bf(aV[rr]);
    }
    __syncthreads();
    if (tid < 64) {
        const uint4* src = (const uint4*)&s_vp[tid][0];   // 16 bf16 = 32 B
        uint4* dst = (uint4*)(VpT + (size_t)tid * B_ROWS + r0);
        dst[0] = src[0]; dst[1] = src[1];
    }
}

// ---------------------------------------------------------------------------
// Kernel B: flash attention, block = 64 q-rows (4 waves x 16), 4-way key
// split. K/V staged block-wide in LDS via global_load_lds, 4-deep buffers,
// counted vmcnt (T4: never 0 in main loop), raw s_barrier.
// grid = 128 qblocks x 4 splits = 512. Partial (O,l) per wave -> ws.
// ---------------------------------------------------------------------------
__global__ __launch_bounds__(256, 2) void attn_kernel(
    const unsigned short* __restrict__ Qp, const unsigned short* __restrict__ Kp,
    const unsigned short* __restrict__ VpT,
    float* __restrict__ Opart, float* __restrict__ lpart)
{
    __shared__ unsigned short s_K[4][64][64];   // [buf][key][d]   (swizzled rows)
    __shared__ unsigned short s_V[4][64][64];   // [buf][d][key]   (swizzled rows)
    __shared__ unsigned short s_P[4][16][72];   // per-wave P tile, padded rows

    const int tid = threadIdx.x;
    const int w = tid >> 6, lane = tid & 63;
    const int l15 = lane & 15, lhi = lane >> 4;
    const int qb = blockIdx.x >> 2, sp = blockIdx.x & 3;
    const int qrow0 = qb * 64 + w * 16;          // this wave's 16 q-rows
    const int key0 = sp * 2048;

    // staging source pattern: lane -> (row8 = lane>>3, chunk c16 = lane&7),
    // global col byte pre-swizzled so linear LDS ends up XOR-swizzled.
    const int r8  = lane >> 3, c16 = lane & 7;
    const int swz_st = (c16 * 16) ^ (r8 << 4);   // within 128B row
    const int swz_rd = (l15 & 7) << 4;           // read-side XOR

    s16x8 QA[2];
#pragma unroll
    for (int kk = 0; kk < 2; ++kk)
        QA[kk] = *(const s16x8*)(Qp + (size_t)(qrow0 + l15) * 64 + kk * 32 + lhi * 8);

    f32x4 accO[4];
#pragma unroll
    for (int ht = 0; ht < 4; ++ht) accO[ht] = (f32x4){0.f, 0.f, 0.f, 0.f};
    float lp[4] = {0.f, 0.f, 0.f, 0.f};
    const f32x4 zero4 = (f32x4){0.f, 0.f, 0.f, 0.f};

    // stage one 64-key tile (K: 8KB, V^T: 8KB) -- 4 gload16 per wave
    auto STAGE = [&](int buf, int t) {
        const int kc0 = key0 + t * 64;
#pragma unroll
        for (int j = 0; j < 2; ++j) {
            const int row = w * 16 + j * 8 + r8;                 // 0..63
            const char* gk = (const char*)Kp + (size_t)(kc0 + row) * 128 + swz_st;
            gl_lds16(gk, &s_K[buf][w * 16 + j * 8][0]);
            const char* gv = (const char*)VpT + (size_t)row * (B_ROWS * 2)
                             + (size_t)kc0 * 2 + swz_st;
            gl_lds16(gv, &s_V[buf][w * 16 + j * 8][0]);
        }
    };

    auto COMPUTE = [&](int buf) {
        const char* Kb = (const char*)&s_K[buf][0][0];
        const char* Vb = (const char*)&s_V[buf][0][0];
        f32x4 accS[4];
#pragma unroll
        for (int nt = 0; nt < 4; ++nt) {
            const int rb = (nt * 16 + l15) * 128;
            s16x8 k0 = *(const s16x8*)(Kb + rb + ((lhi * 16)      ^ swz_rd));
            s16x8 k1 = *(const s16x8*)(Kb + rb + ((64 + lhi * 16) ^ swz_rd));
            accS[nt] = __builtin_amdgcn_mfma_f32_16x16x32_bf16(QA[0], k0, zero4, 0, 0, 0);
            accS[nt] = __builtin_amdgcn_mfma_f32_16x16x32_bf16(QA[1], k1, accS[nt], 0, 0, 0);
        }
        // P = exp2(S); Qp carries log2(e). C-layout: row=lhi*4+reg, col=l15.
#pragma unroll
        for (int nt = 0; nt < 4; ++nt)
#pragma unroll
            for (int reg = 0; reg < 4; ++reg) {
                float p = EXP2(accS[nt][reg]);
                lp[reg] += p;
                s_P[w][lhi * 4 + reg][nt * 16 + l15] = f2bf(p);
            }
        s16x8 PA[2];
#pragma unroll
        for (int kk = 0; kk < 2; ++kk)
            PA[kk] = *(const s16x8*)&s_P[w][l15][kk * 32 + lhi * 8];
#pragma unroll
        for (int ht = 0; ht < 4; ++ht) {
            const int rb = (ht * 16 + l15) * 128;
            s16x8 v0 = *(const s16x8*)(Vb + rb + ((lhi * 16)      ^ swz_rd));
            s16x8 v1 = *(const s16x8*)(Vb + rb + ((64 + lhi * 16) ^ swz_rd));
            accO[ht] = __builtin_amdgcn_mfma_f32_16x16x32_bf16(PA[0], v0, accO[ht], 0, 0, 0);
            accO[ht] = __builtin_amdgcn_mfma_f32_16x16x32_bf16(PA[1], v1, accO[ht], 0, 0, 0);
        }
    };

    // ---- software pipeline: 3 tiles in flight, counted vmcnt.
    // Per-wave loads/tile = 4. Outstanding at wait = 12 -> vmcnt(8) completes
    // the oldest tile. Buffer written at iter t is (t+3)&3 = (t-1)&3, whose
    // last readers all passed this iteration's barrier first (safe).
    STAGE(0, 0); STAGE(1, 1); STAGE(2, 2);
#pragma unroll 1
    for (int t = 0; t < 29; ++t) {
        asm volatile("s_waitcnt vmcnt(8)" ::: "memory");
        __builtin_amdgcn_s_barrier();
        asm volatile("" ::: "memory");
        COMPUTE(t & 3);
        STAGE((t + 3) & 3, t + 3);
    }
    asm volatile("s_waitcnt vmcnt(8)" ::: "memory");
    __builtin_amdgcn_s_barrier();
    asm volatile("" ::: "memory");
    COMPUTE(29 & 3);
    asm volatile("s_waitcnt vmcnt(4)" ::: "memory");
    __builtin_amdgcn_s_barrier();
    asm volatile("" ::: "memory");
    COMPUTE(30 & 3);
    asm volatile("s_waitcnt vmcnt(0)" ::: "memory");
    __builtin_amdgcn_s_barrier();
    asm volatile("" ::: "memory");
    COMPUTE(31 & 3);

    // row-sum reduce over l15 groups; lanes l15==0 hold rows lhi*4+reg
#pragma unroll
    for (int reg = 0; reg < 4; ++reg) {
        float v = lp[reg];
        v += __shfl_xor(v, 1, 64); v += __shfl_xor(v, 2, 64);
        v += __shfl_xor(v, 4, 64); v += __shfl_xor(v, 8, 64);
        lp[reg] = v;
    }
    if (l15 == 0) {
#pragma unroll
        for (int reg = 0; reg < 4; ++reg)
            lpart[(size_t)sp * B_ROWS + qrow0 + lhi * 4 + reg] = lp[reg];
    }
#pragma unroll
    for (int ht = 0; ht < 4; ++ht)
#pragma unroll
        for (int reg = 0; reg < 4; ++reg)
            Opart[(size_t)sp * (B_ROWS * 64)
                  + (size_t)(qrow0 + lhi * 4 + reg) * 64 + ht * 16 + l15] = accO[ht][reg];
}

// ---------------------------------------------------------------------------
// Kernel C: merge 4 key-splits + epilogue relu((vw@W1)/sqrt(1+eps)), h@W2,
// sigmoid(fm + .). grid = 512 (16 rows each), block = 256.
// ---------------------------------------------------------------------------
__global__ __launch_bounds__(256) void merge_kernel(
    const float* __restrict__ Opart, const float* __restrict__ lpart,
    const float* __restrict__ fm,
    const float* __restrict__ W1, const float* __restrict__ b1,
    const float* __restrict__ W2, const float* __restrict__ b2,
    float* __restrict__ out)
{
    __shared__ float s_Os[16][64];
    __shared__ float s_L[16];
    __shared__ float s_ep[16][17];

    const int tid = threadIdx.x;
    const int qt = blockIdx.x;
    const int row0 = qt * 16;

#pragma unroll
    for (int i = 0; i < 4; ++i) {
        int idx = i * 256 + tid, r = idx >> 6, c = idx & 63;
        float o = 0.f;
#pragma unroll
        for (int sp2 = 0; sp2 < 4; ++sp2)
            o += Opart[(size_t)sp2 * (B_ROWS * 64) + (size_t)(row0 + r) * 64 + c];
        s_Os[r][c] = o;
    }
    if (tid < 16) {
        float L = 0.f;
#pragma unroll
        for (int sp2 = 0; sp2 < 4; ++sp2) L += lpart[(size_t)sp2 * B_ROWS + row0 + tid];
        s_L[tid] = L;
    }
    __syncthreads();
    {
        const int r = tid & 15, jg = tid >> 4;
        const float invL = 1.0f / s_L[r];
        const float invs = 0.9999950000374997f;   // 1/sqrt(1+1e-5)
        float d[4] = {0.f, 0.f, 0.f, 0.f};
#pragma unroll 8
        for (int c = 0; c < 64; ++c) {
            float o = s_Os[r][c];
#pragma unroll
            for (int jj = 0; jj < 4; ++jj) d[jj] += o * W1[c * 64 + jg * 4 + jj];
        }
        float acc = 0.f;
#pragma unroll
        for (int jj = 0; jj < 4; ++jj) {
            int j = jg * 4 + jj;
            float hv = invs * (d[jj] * invL + b1[j]);
            hv = fmaxf(hv, 0.f);
            acc += hv * W2[j];
        }
        s_ep[r][jg] = acc;
    }
    __syncthreads();
    if (tid < 16) {
        int r = tid;
        float s = 0.f;
#pragma unroll
        for (int jg = 0; jg < 16; ++jg) s += s_ep[r][jg];
        float z = fm[row0 + r] + s + b2[0];
        out[row0 + r] = 1.0f / (1.0f + __expf(-z));
    }
}

extern "C" void kernel_launch(void* const* d_in, const int* in_sizes, int n_in,
                              void* d_out, int out_size, void* d_ws, size_t ws_size,
                              hipStream_t stream) {
    const float* bd   = (const float*)d_in[0];
    const float* fm_w = (const float*)d_in[1];
    const float* fm_b = (const float*)d_in[2];
    const float* W_DA = (const float*)d_in[3];
    const float* b_DA = (const float*)d_in[4];
    const float* W_DM = (const float*)d_in[5];
    const float* b_DM = (const float*)d_in[6];
    const float* hDA  = (const float*)d_in[7];
    const float* hDM  = (const float*)d_in[8];
    const float* hCA  = (const float*)d_in[9];
    const float* hCM  = (const float*)d_in[10];
    const float* fvDA = (const float*)d_in[11];
    const float* fvDM = (const float*)d_in[12];
    const float* fvCA = (const float*)d_in[13];
    const float* fvCM = (const float*)d_in[14];
    const float* Qw   = (const float*)d_in[15];
    const float* Kw   = (const float*)d_in[16];
    const float* Vw   = (const float*)d_in[17];
    const float* W1   = (const float*)d_in[18];
    const float* b1   = (const float*)d_in[19];
    const float* W2   = (const float*)d_in[20];
    const float* b2   = (const float*)d_in[21];

    char* ws = (char*)d_ws;
    float*          fmv   = (float*)ws;                                   // 32 KB
    unsigned short* Qp    = (unsigned short*)(ws + (32u<<10));            // 1 MB
    unsigned short* Kp    = (unsigned short*)(ws + (32u<<10) + (1u<<20)); // 1 MB
    unsigned short* VpT   = (unsigned short*)(ws + (32u<<10) + (2u<<20)); // 1 MB
    unsigned short* WbT   = (unsigned short*)(ws + (32u<<10) + (3u<<20)); // 192 KB (reserve 256 KB)
    float*          Opart = (float*)(ws + (32u<<10) + (3u<<20) + (256u<<10)); // 8 MB
    float*          lpart = (float*)(ws + (32u<<10) + (3u<<20) + (256u<<10) + (8u<<20)); // 128 KB

    hipLaunchKernelGGL(wconv_kernel, dim3(128), dim3(256), 0, stream,
        W_DA, W_DM, WbT);

    hipLaunchKernelGGL(prep_kernel, dim3(512), dim3(256), 0, stream,
        bd, fm_w, fm_b, b_DA, b_DM, WbT, hDA, hDM, hCA, hCM,
        fvDA, fvDM, fvCA, fvCM, Qw, Kw, Vw, fmv, Qp, Kp, VpT);

    hipLaunchKernelGGL(attn_kernel, dim3(512), dim3(256), 0, stream,
        Qp, Kp, VpT, Opart, lpart);

    hipLaunchKernelGGL(merge_kernel, dim3(512), dim3(256), 0, stream,
        Opart, lpart, fmv, W1, b1, W2, b2, (float*)d_out);
}

// Round 8
// 182.817 us; speedup vs baseline: 1.7755x; 1.0159x over previous
//
#include <hip/hip_runtime.h>
#include <hip/hip_bf16.h>

#define B_ROWS 8192
#define FEAT   1538

typedef float f32x4 __attribute__((ext_vector_type(4)));
typedef float f32x2 __attribute__((ext_vector_type(2)));
typedef short s16x8 __attribute__((ext_vector_type(8)));

#if __has_builtin(__builtin_amdgcn_exp2f)
#define EXP2(x) __builtin_amdgcn_exp2f(x)
#else
#define EXP2(x) exp2f(x)
#endif

__device__ __forceinline__ unsigned short f2bf(float x) {
    __hip_bfloat16 h = __float2bfloat16(x);
    return *reinterpret_cast<unsigned short*>(&h);
}

// pack 2 f32 -> 1 dword of 2 bf16 (v_cvt_pk_bf16_f32 via HIP intrinsic)
__device__ __forceinline__ unsigned int pk2bf(float a, float b) {
    float2 f2; f2.x = a; f2.y = b;
    __hip_bfloat162 h2 = __float22bfloat162_rn(f2);
    return *reinterpret_cast<unsigned int*>(&h2);
}

// async global->LDS, 16B per lane. LDS dest must be wave-uniform base
// (HW writes base + lane*16); global src is per-lane.
__device__ __forceinline__ void gl_lds16(const void* g, void* l) {
    __builtin_amdgcn_global_load_lds(
        (const __attribute__((address_space(1))) unsigned int*)g,
        (__attribute__((address_space(3))) unsigned int*)l, 16, 0, 0);
}

// ---------------------------------------------------------------------------
// Kernel 0: transpose+convert W_DA/W_DM (f32 [768][64]) -> bf16 WbT [2][64][768]
// ---------------------------------------------------------------------------
__global__ __launch_bounds__(256) void wconv_kernel(
    const float* __restrict__ W_DA, const float* __restrict__ W_DM,
    unsigned short* __restrict__ WbT)
{
    const int m   = blockIdx.x >> 6;     // 0 = DA, 1 = DM
    const int col = blockIdx.x & 63;
    const float* W = m ? W_DM : W_DA;
    unsigned short* dst = WbT + ((size_t)m * 64 + col) * 768;
#pragma unroll
    for (int i = 0; i < 3; ++i) {
        int k = i * 256 + threadIdx.x;
        dst[k] = f2bf(W[(size_t)k * 64 + col]);
    }
}

// ---------------------------------------------------------------------------
// Kernel A: per 16-row block -> fm, X, and bf16 Qp/Kp/VpT.
// Phase 1 two K-passes (DA then DM) sharing one 768-col staging buffer:
// LDS ~48 KB => 3 blocks/CU. block = 256 (4 waves). grid = 512.
// ---------------------------------------------------------------------------
__global__ __launch_bounds__(256, 3) void prep_kernel(
    const float* __restrict__ bd, const float* __restrict__ fm_w, const float* __restrict__ fm_b,
    const float* __restrict__ b_DA, const float* __restrict__ b_DM,
    const unsigned short* __restrict__ WbT,
    const float* __restrict__ hDA, const float* __restrict__ hDM,
    const float* __restrict__ hCA, const float* __restrict__ hCM,
    const float* __restrict__ fvDA, const float* __restrict__ fvDM,
    const float* __restrict__ fvCA, const float* __restrict__ fvCM,
    const float* __restrict__ Qw, const float* __restrict__ Kw, const float* __restrict__ Vw,
    float* __restrict__ fm_out, unsigned short* __restrict__ Qp,
    unsigned short* __restrict__ Kp, unsigned short* __restrict__ VpT)
{
    __shared__ unsigned short s_bd16[16][776];    // bf16 rows, one 768-col pass (pad)
    __shared__ float s_iDA [64][16];
    __shared__ float s_iDA2[64][16];
    __shared__ float s_iDM [64][16];
    __shared__ float s_iDM2[64][16];
    __shared__ float s_sc[16][4];                 // sB_DA, sB_DM, cA, cM per row
    __shared__ float s_fmrow[16];
    __shared__ float s_rsum[2][4][16];            // [mat][wave][row]
    __shared__ float s_X[64][16];
    __shared__ unsigned short s_vp[64][16];

    const int tid  = threadIdx.x;
    const int w    = tid >> 6;
    const int lane = tid & 63;
    const int l15  = lane & 15, lhi = lane >> 4;
    const int r0   = blockIdx.x * 16;

    // ---- Phase 1: two passes. Stage 768 bf16 cols; MFMA one matrix per pass.
    float fmp = 0.f;
    const int srow = tid >> 4, scg = tid & 15;
#pragma unroll
    for (int p = 0; p < 2; ++p) {
        const float* bdr = bd + (size_t)(r0 + srow) * FEAT + p * 768;
        const float* fwr = fm_w + p * 768;
#pragma unroll 4
        for (int s = 0; s < 12; ++s) {
            int c = (scg + s * 16) * 4;
            f32x2 v0 = *(const f32x2*)(bdr + c);
            f32x2 v1 = *(const f32x2*)(bdr + c + 2);
            f32x2 g0 = *(const f32x2*)(fwr + c);
            f32x2 g1 = *(const f32x2*)(fwr + c + 2);
            fmp += v0.x * g0.x + v0.y * g0.y + v1.x * g1.x + v1.y * g1.y;
            ushort4 pk;
            pk.x = f2bf(v0.x); pk.y = f2bf(v0.y); pk.z = f2bf(v1.x); pk.w = f2bf(v1.y);
            *(ushort4*)&s_bd16[srow][c] = pk;
        }
        __syncthreads();

        // wave w computes output cols w*16 .. w*16+15 of matrix p
        const unsigned short* WT = WbT + (size_t)p * 64 * 768 + (size_t)(w * 16 + l15) * 768;
        f32x4 c0 = {0.f, 0.f, 0.f, 0.f};
#pragma unroll 6
        for (int s = 0; s < 24; ++s) {
            s16x8 A = *(const s16x8*)&s_bd16[l15][s * 32 + lhi * 8];
            s16x8 B = *(const s16x8*)(WT + s * 32 + lhi * 8);
            c0 = __builtin_amdgcn_mfma_f32_16x16x32_bf16(A, B, c0, 0, 0, 0);
        }
        const float* bb = p ? b_DM : b_DA;
        const float bias = bb[w * 16 + l15];
        float (*iA)[16]  = p ? s_iDM  : s_iDA;
        float (*iA2)[16] = p ? s_iDM2 : s_iDA2;
        float rsum[4];
#pragma unroll
        for (int reg = 0; reg < 4; ++reg) {
            const int row = lhi * 4 + reg;           // C-layout: col=l15, row=lhi*4+reg
            float v = c0[reg] + bias;
            iA [w * 16 + l15][row] = v;
            iA2[w * 16 + l15][row] = v * v;
            float rs = v;                            // row-sum over this wave's 16 cols
            rs += __shfl_xor(rs, 1, 64); rs += __shfl_xor(rs, 2, 64);
            rs += __shfl_xor(rs, 4, 64); rs += __shfl_xor(rs, 8, 64);
            rsum[reg] = rs;
        }
        if (l15 == 0) {
#pragma unroll
            for (int reg = 0; reg < 4; ++reg)
                s_rsum[p][w][lhi * 4 + reg] = rsum[reg];
        }
        __syncthreads();
    }

    // fm partial reduce (within each 16-thread row group)
    fmp += __shfl_xor(fmp, 1, 64); fmp += __shfl_xor(fmp, 2, 64);
    fmp += __shfl_xor(fmp, 4, 64); fmp += __shfl_xor(fmp, 8, 64);
    if (scg == 0) s_fmrow[srow] = fmp;
    __syncthreads();

    if (tid < 16) {
        const int r = tid;
        float cA = bd[(size_t)(r0 + r) * FEAT + 1536];
        float cM = bd[(size_t)(r0 + r) * FEAT + 1537];
        s_sc[r][0] = s_rsum[0][0][r] + s_rsum[0][1][r] + s_rsum[0][2][r] + s_rsum[0][3][r];
        s_sc[r][1] = s_rsum[1][0][r] + s_rsum[1][1][r] + s_rsum[1][2][r] + s_rsum[1][3][r];
        s_sc[r][2] = cA; s_sc[r][3] = cM;
        fm_out[r0 + r] = s_fmrow[r] + cA * fm_w[1536] + cM * fm_w[1537] + fm_b[0];
    }
    __syncthreads();

    // ---- Phase 2: bi-pooling sums + X (wave w owns rows 4w..4w+3, lane = h)
    float sADA[4] = {0,0,0,0}, sqDA[4] = {0,0,0,0};
    float sADM[4] = {0,0,0,0}, sqDM[4] = {0,0,0,0};
    const int rbase = w * 4;
#pragma unroll 8
    for (int e2 = 0; e2 < 64; ++e2) {
        float ha = hDA[e2 * 64 + lane], hm = hDM[e2 * 64 + lane];
        float ha2 = ha * ha, hm2 = hm * hm;
        f32x4 ia  = *(const f32x4*)&s_iDA [e2][rbase];
        f32x4 ia2 = *(const f32x4*)&s_iDA2[e2][rbase];
        f32x4 im  = *(const f32x4*)&s_iDM [e2][rbase];
        f32x4 im2 = *(const f32x4*)&s_iDM2[e2][rbase];
#pragma unroll
        for (int rr = 0; rr < 4; ++rr) {
            sADA[rr] += ia[rr] * ha;  sqDA[rr] += ia2[rr] * ha2;
            sADM[rr] += im[rr] * hm;  sqDM[rr] += im2[rr] * hm2;
        }
    }
    {
        const float fva = fvDA[lane], fvm = fvDM[lane];
        const float fvca = fvCA[lane], fvcm = fvCM[lane];
        const float hca = hCA[lane],  hcm = hCM[lane];
#pragma unroll
        for (int rr = 0; rr < 4; ++rr) {
            int r = rbase + rr;
            float sBDA = s_sc[r][0], sBDM = s_sc[r][1];
            float cA = s_sc[r][2],   cM = s_sc[r][3];
            float biA = 0.5f * (sADA[rr] * sADA[rr] - sqDA[rr]);
            float biM = 0.5f * (sADM[rr] * sADM[rr] - sqDM[rr]);
            float X = biA + biM
                + sADA[rr] * (fvm * sBDM + fvca * cA + fvcm * cM)
                + sADM[rr] * (fva * sBDA + fvca * cA + fvcm * cM)
                + cA * hca * (fva * sBDA + fvm * sBDM + fvcm * cM)
                + cM * hcm * (fva * sBDA + fvm * sBDM + fvca * cA);
            s_X[lane][r] = X;
        }
    }
    __syncthreads();

    // ---- Phase 3: QKV projection (lane = output col j)
    float aQ[4] = {0,0,0,0}, aK[4] = {0,0,0,0}, aV[4] = {0,0,0,0};
#pragma unroll 8
    for (int h2 = 0; h2 < 64; ++h2) {
        float q = Qw[h2 * 64 + lane], k = Kw[h2 * 64 + lane], v = Vw[h2 * 64 + lane];
        f32x4 x = *(const f32x4*)&s_X[h2][rbase];
#pragma unroll
        for (int rr = 0; rr < 4; ++rr) {
            aQ[rr] += x[rr] * q; aK[rr] += x[rr] * k; aV[rr] += x[rr] * v;
        }
    }
    const float LOG2E = 1.4426950408889634f;
#pragma unroll
    for (int rr = 0; rr < 4; ++rr) {
        int r = rbase + rr;
        Qp[(size_t)(r0 + r) * 64 + lane] = f2bf(aQ[rr] * LOG2E);
        Kp[(size_t)(r0 + r) * 64 + lane] = f2bf(aK[rr]);
        s_vp[lane][r] = f2bf(aV[rr]);
    }
    __syncthreads();
    if (tid < 64) {
        const uint4* src = (const uint4*)&s_vp[tid][0];   // 16 bf16 = 32 B
        uint4* dst = (uint4*)(VpT + (size_t)tid * B_ROWS + r0);
        dst[0] = src[0]; dst[1] = src[1];
    }
}

// ---------------------------------------------------------------------------
// Kernel B: flash attention. Swapped QK^T (mfma(K,Q)) so each lane holds 4
// CONTIGUOUS keys at fixed q -> P written as 1 ds_write_b64 per nt (was 16
// scalar b16 per tile): DS ops/tile/wave 34 -> 22. Pipeline identical to R6
// (4-deep LDS dbuf, counted vmcnt, raw s_barrier). grid 512, 4 waves.
// ---------------------------------------------------------------------------
__global__ __launch_bounds__(256, 2) void attn_kernel(
    const unsigned short* __restrict__ Qp, const unsigned short* __restrict__ Kp,
    const unsigned short* __restrict__ VpT,
    float* __restrict__ Opart, float* __restrict__ lpart)
{
    __shared__ unsigned short s_K[4][64][64];   // [buf][key][d]   (swizzled rows)
    __shared__ unsigned short s_V[4][64][64];   // [buf][d][key]   (swizzled rows)
    __shared__ unsigned short s_P[4][16][72];   // per-wave P tile [q][key], padded rows

    const int tid = threadIdx.x;
    const int w = tid >> 6, lane = tid & 63;
    const int l15 = lane & 15, lhi = lane >> 4;
    const int qb = blockIdx.x >> 2, sp = blockIdx.x & 3;
    const int qrow0 = qb * 64 + w * 16;          // this wave's 16 q-rows
    const int key0 = sp * 2048;

    // staging source pattern: lane -> (row8 = lane>>3, chunk c16 = lane&7),
    // global col byte pre-swizzled so linear LDS ends up XOR-swizzled.
    const int r8  = lane >> 3, c16 = lane & 7;
    const int swz_st = (c16 * 16) ^ (r8 << 4);   // within 128B row
    const int swz_rd = (l15 & 7) << 4;           // read-side XOR

    s16x8 QA[2];
#pragma unroll
    for (int kk = 0; kk < 2; ++kk)
        QA[kk] = *(const s16x8*)(Qp + (size_t)(qrow0 + l15) * 64 + kk * 32 + lhi * 8);

    f32x4 accO[4];
#pragma unroll
    for (int ht = 0; ht < 4; ++ht) accO[ht] = (f32x4){0.f, 0.f, 0.f, 0.f};
    float lp = 0.f;
    const f32x4 zero4 = (f32x4){0.f, 0.f, 0.f, 0.f};

    // stage one 64-key tile (K: 8KB, V^T: 8KB) -- 4 gload16 per wave
    auto STAGE = [&](int buf, int t) {
        const int kc0 = key0 + t * 64;
#pragma unroll
        for (int j = 0; j < 2; ++j) {
            const int row = w * 16 + j * 8 + r8;                 // 0..63
            const char* gk = (const char*)Kp + (size_t)(kc0 + row) * 128 + swz_st;
            gl_lds16(gk, &s_K[buf][w * 16 + j * 8][0]);
            const char* gv = (const char*)VpT + (size_t)row * (B_ROWS * 2)
                             + (size_t)kc0 * 2 + swz_st;
            gl_lds16(gv, &s_V[buf][w * 16 + j * 8][0]);
        }
    };

    auto COMPUTE = [&](int buf) {
        const char* Kb = (const char*)&s_K[buf][0][0];
        const char* Vb = (const char*)&s_V[buf][0][0];
        f32x4 accS[4];
#pragma unroll
        for (int nt = 0; nt < 4; ++nt) {
            const int rb = (nt * 16 + l15) * 128;
            s16x8 k0 = *(const s16x8*)(Kb + rb + ((lhi * 16)      ^ swz_rd));
            s16x8 k1 = *(const s16x8*)(Kb + rb + ((64 + lhi * 16) ^ swz_rd));
            // swapped: D[key][q] -> lane holds keys nt*16+lhi*4.. (contig), q=l15
            accS[nt] = __builtin_amdgcn_mfma_f32_16x16x32_bf16(k0, QA[0], zero4, 0, 0, 0);
            accS[nt] = __builtin_amdgcn_mfma_f32_16x16x32_bf16(k1, QA[1], accS[nt], 0, 0, 0);
        }
        // P = exp2(S); pack 4 contiguous keys -> one b64 write per nt.
#pragma unroll
        for (int nt = 0; nt < 4; ++nt) {
            float p0 = EXP2(accS[nt][0]);
            float p1 = EXP2(accS[nt][1]);
            float p2 = EXP2(accS[nt][2]);
            float p3 = EXP2(accS[nt][3]);
            lp += (p0 + p1) + (p2 + p3);
            uint2 pk;
            pk.x = pk2bf(p0, p1);
            pk.y = pk2bf(p2, p3);
            *(uint2*)&s_P[w][l15][nt * 16 + lhi * 4] = pk;
        }
        s16x8 PA[2];
#pragma unroll
        for (int kk = 0; kk < 2; ++kk)
            PA[kk] = *(const s16x8*)&s_P[w][l15][kk * 32 + lhi * 8];
#pragma unroll
        for (int ht = 0; ht < 4; ++ht) {
            const int rb = (ht * 16 + l15) * 128;
            s16x8 v0 = *(const s16x8*)(Vb + rb + ((lhi * 16)      ^ swz_rd));
            s16x8 v1 = *(const s16x8*)(Vb + rb + ((64 + lhi * 16) ^ swz_rd));
            accO[ht] = __builtin_amdgcn_mfma_f32_16x16x32_bf16(PA[0], v0, accO[ht], 0, 0, 0);
            accO[ht] = __builtin_amdgcn_mfma_f32_16x16x32_bf16(PA[1], v1, accO[ht], 0, 0, 0);
        }
    };

    // ---- software pipeline: 3 tiles in flight, counted vmcnt (as R6).
    STAGE(0, 0); STAGE(1, 1); STAGE(2, 2);
#pragma unroll 1
    for (int t = 0; t < 29; ++t) {
        asm volatile("s_waitcnt vmcnt(8)" ::: "memory");
        __builtin_amdgcn_s_barrier();
        asm volatile("" ::: "memory");
        COMPUTE(t & 3);
        STAGE((t + 3) & 3, t + 3);
    }
    asm volatile("s_waitcnt vmcnt(8)" ::: "memory");
    __builtin_amdgcn_s_barrier();
    asm volatile("" ::: "memory");
    COMPUTE(29 & 3);
    asm volatile("s_waitcnt vmcnt(4)" ::: "memory");
    __builtin_amdgcn_s_barrier();
    asm volatile("" ::: "memory");
    COMPUTE(30 & 3);
    asm volatile("s_waitcnt vmcnt(0)" ::: "memory");
    __builtin_amdgcn_s_barrier();
    asm volatile("" ::: "memory");
    COMPUTE(31 & 3);

    // lp holds partial row-sum for q=l15 over this lane's key subset;
    // combine the 4 lhi groups.
    lp += __shfl_xor(lp, 16, 64);
    lp += __shfl_xor(lp, 32, 64);
    if (lhi == 0)
        lpart[(size_t)sp * B_ROWS + qrow0 + l15] = lp;

#pragma unroll
    for (int ht = 0; ht < 4; ++ht)
#pragma unroll
        for (int reg = 0; reg < 4; ++reg)
            Opart[(size_t)sp * (B_ROWS * 64)
                  + (size_t)(qrow0 + lhi * 4 + reg) * 64 + ht * 16 + l15] = accO[ht][reg];
}

// ---------------------------------------------------------------------------
// Kernel C: merge 4 key-splits + epilogue relu((vw@W1)/sqrt(1+eps)), h@W2,
// sigmoid(fm + .). grid = 512 (16 rows each), block = 256.
// ---------------------------------------------------------------------------
__global__ __launch_bounds__(256) void merge_kernel(
    const float* __restrict__ Opart, const float* __restrict__ lpart,
    const float* __restrict__ fm,
    const float* __restrict__ W1, const float* __restrict__ b1,
    const float* __restrict__ W2, const float* __restrict__ b2,
    float* __restrict__ out)
{
    __shared__ float s_Os[16][64];
    __shared__ float s_L[16];
    __shared__ float s_ep[16][17];

    const int tid = threadIdx.x;
    const int qt = blockIdx.x;
    const int row0 = qt * 16;

#pragma unroll
    for (int i = 0; i < 4; ++i) {
        int idx = i * 256 + tid, r = idx >> 6, c = idx & 63;
        float o = 0.f;
#pragma unroll
        for (int sp2 = 0; sp2 < 4; ++sp2)
            o += Opart[(size_t)sp2 * (B_ROWS * 64) + (size_t)(row0 + r) * 64 + c];
        s_Os[r][c] = o;
    }
    if (tid < 16) {
        float L = 0.f;
#pragma unroll
        for (int sp2 = 0; sp2 < 4; ++sp2) L += lpart[(size_t)sp2 * B_ROWS + row0 + tid];
        s_L[tid] = L;
    }
    __syncthreads();
    {
        const int r = tid & 15, jg = tid >> 4;
        const float invL = 1.0f / s_L[r];
        const float invs = 0.9999950000374997f;   // 1/sqrt(1+1e-5)
        float d[4] = {0.f, 0.f, 0.f, 0.f};
#pragma unroll 8
        for (int c = 0; c < 64; ++c) {
            float o = s_Os[r][c];
#pragma unroll
            for (int jj = 0; jj < 4; ++jj) d[jj] += o * W1[c * 64 + jg * 4 + jj];
        }
        float acc = 0.f;
#pragma unroll
        for (int jj = 0; jj < 4; ++jj) {
            int j = jg * 4 + jj;
            float hv = invs * (d[jj] * invL + b1[j]);
            hv = fmaxf(hv, 0.f);
            acc += hv * W2[j];
        }
        s_ep[r][jg] = acc;
    }
    __syncthreads();
    if (tid < 16) {
        int r = tid;
        float s = 0.f;
#pragma unroll
        for (int jg = 0; jg < 16; ++jg) s += s_ep[r][jg];
        float z = fm[row0 + r] + s + b2[0];
        out[row0 + r] = 1.0f / (1.0f + __expf(-z));
    }
}

extern "C" void kernel_launch(void* const* d_in, const int* in_sizes, int n_in,
                              void* d_out, int out_size, void* d_ws, size_t ws_size,
                              hipStream_t stream) {
    const float* bd   = (const float*)d_in[0];
    const float* fm_w = (const float*)d_in[1];
    const float* fm_b = (const float*)d_in[2];
    const float* W_DA = (const float*)d_in[3];
    const float* b_DA = (const float*)d_in[4];
    const float* W_DM = (const float*)d_in[5];
    const float* b_DM = (const float*)d_in[6];
    const float* hDA  = (const float*)d_in[7];
    const float* hDM  = (const float*)d_in[8];
    const float* hCA  = (const float*)d_in[9];
    const float* hCM  = (const float*)d_in[10];
    const float* fvDA = (const float*)d_in[11];
    const float* fvDM = (const float*)d_in[12];
    const float* fvCA = (const float*)d_in[13];
    const float* fvCM = (const float*)d_in[14];
    const float* Qw   = (const float*)d_in[15];
    const float* Kw   = (const float*)d_in[16];
    const float* Vw   = (const float*)d_in[17];
    const float* W1   = (const float*)d_in[18];
    const float* b1   = (const float*)d_in[19];
    const float* W2   = (const float*)d_in[20];
    const float* b2   = (const float*)d_in[21];

    char* ws = (char*)d_ws;
    float*          fmv   = (float*)ws;                                   // 32 KB
    unsigned short* Qp    = (unsigned short*)(ws + (32u<<10));            // 1 MB
    unsigned short* Kp    = (unsigned short*)(ws + (32u<<10) + (1u<<20)); // 1 MB
    unsigned short* VpT   = (unsigned short*)(ws + (32u<<10) + (2u<<20)); // 1 MB
    unsigned short* WbT   = (unsigned short*)(ws + (32u<<10) + (3u<<20)); // 192 KB (reserve 256 KB)
    float*          Opart = (float*)(ws + (32u<<10) + (3u<<20) + (256u<<10)); // 8 MB
    float*          lpart = (float*)(ws + (32u<<10) + (3u<<20) + (256u<<10) + (8u<<20)); // 128 KB

    hipLaunchKernelGGL(wconv_kernel, dim3(128), dim3(256), 0, stream,
        W_DA, W_DM, WbT);

    hipLaunchKernelGGL(prep_kernel, dim3(512), dim3(256), 0, stream,
        bd, fm_w, fm_b, b_DA, b_DM, WbT, hDA, hDM, hCA, hCM,
        fvDA, fvDM, fvCA, fvCM, Qw, Kw, Vw, fmv, Qp, Kp, VpT);

    hipLaunchKernelGGL(attn_kernel, dim3(512), dim3(256), 0, stream,
        Qp, Kp, VpT, Opart, lpart);

    hipLaunchKernelGGL(merge_kernel, dim3(512), dim3(256), 0, stream,
        Opart, lpart, fmv, W1, b1, W2, b2, (float*)d_out);
}